// Round 1
// baseline (182.671 us; speedup 1.0000x reference)
//
#include <hip/hip_runtime.h>

#define VIEWS 512
#define DETS  512
#define HH    256
#define WW    256
#define NS    384

__global__ void interleave_kernel(const float* __restrict__ img, float2* __restrict__ dst) {
    int i = blockIdx.x * blockDim.x + threadIdx.x;
    if (i < HH * WW) dst[i] = make_float2(img[i], img[HH * WW + i]);
}

template <bool INTERLEAVED>
__global__ __launch_bounds__(256) void project_kernel(
    const float* __restrict__ img,   // planar (2,1,H,W)
    const float2* __restrict__ img2, // interleaved (H,W) of (c0,c1)
    const float* __restrict__ opt,
    float* __restrict__ out)
{
    int idx = blockIdx.x * blockDim.x + threadIdx.x;
    int v = idx >> 9;          // view
    int j = idx & (DETS - 1);  // detector

    float dImg = opt[4], dDet = opt[5], ang0 = opt[6], dAng = opt[7];
    float s2r = opt[8], d2r = opt[9], binshift = opt[10];

    float beta = ang0 + dAng * (float)v;
    float cb = cosf(beta), sb = sinf(beta);
    float u = ((float)j - (DETS - 1) * 0.5f) * dDet + binshift;

    float srcx = s2r * cb, srcy = s2r * sb;
    float dx = -d2r * cb - u * sb - srcx;
    float dy = -d2r * sb + u * cb - srcy;
    float inv = rsqrtf(dx * dx + dy * dy);
    dx *= inv; dy *= inv;

    float R  = 0.5f * sqrtf((float)(HH * HH + WW * WW)) * dImg;
    float dl = 2.0f * R / (float)NS;
    float t0 = s2r - R + 0.5f * dl;
    float invD = 1.0f / dImg;

    float px0 = (srcx + dx * t0) * invD + (WW - 1) * 0.5f;
    float py0 = (srcy + dy * t0) * invD + (HH - 1) * 0.5f;
    float sx = dx * dl * invD;
    float sy = dy * dl * invD;

    float acc0 = 0.0f, acc1 = 0.0f;

    for (int s = 0; s < NS; ++s) {
        float px = fmaf((float)s, sx, px0);
        float py = fmaf((float)s, sy, py0);
        // any nonzero contribution requires px in (-1, W) and py in (-1, H)
        if (px > -1.0f && px < (float)WW && py > -1.0f && py < (float)HH) {
            float x0 = floorf(px), y0 = floorf(py);
            float wx = px - x0, wy = py - y0;
            int x0i = (int)x0, y0i = (int)y0;
            int x1i = x0i + 1, y1i = y0i + 1;

            // given px in (-1,W): x0i in [-1, W-1], x1i in [0, W]
            bool bx0 = (x0i >= 0);
            bool bx1 = (x1i <= WW - 1);
            bool by0 = (y0i >= 0);
            bool by1 = (y1i <= HH - 1);

            int xc0 = bx0 ? x0i : 0;
            int xc1 = bx1 ? x1i : (WW - 1);
            int yc0 = by0 ? y0i : 0;
            int yc1 = by1 ? y1i : (HH - 1);

            float w00 = (1.0f - wx) * (1.0f - wy);
            float w01 = wx * (1.0f - wy);
            float w10 = (1.0f - wx) * wy;
            float w11 = wx * wy;
            w00 = (bx0 & by0) ? w00 : 0.0f;
            w01 = (bx1 & by0) ? w01 : 0.0f;
            w10 = (bx0 & by1) ? w10 : 0.0f;
            w11 = (bx1 & by1) ? w11 : 0.0f;

            int r0 = yc0 * WW, r1 = yc1 * WW;

            if (INTERLEAVED) {
                float2 v00 = img2[r0 + xc0];
                float2 v01 = img2[r0 + xc1];
                float2 v10 = img2[r1 + xc0];
                float2 v11 = img2[r1 + xc1];
                acc0 = fmaf(w00, v00.x, acc0);
                acc1 = fmaf(w00, v00.y, acc1);
                acc0 = fmaf(w01, v01.x, acc0);
                acc1 = fmaf(w01, v01.y, acc1);
                acc0 = fmaf(w10, v10.x, acc0);
                acc1 = fmaf(w10, v10.y, acc1);
                acc0 = fmaf(w11, v11.x, acc0);
                acc1 = fmaf(w11, v11.y, acc1);
            } else {
                const float* p0 = img;
                const float* p1 = img + HH * WW;
                acc0 = fmaf(w00, p0[r0 + xc0], acc0);
                acc0 = fmaf(w01, p0[r0 + xc1], acc0);
                acc0 = fmaf(w10, p0[r1 + xc0], acc0);
                acc0 = fmaf(w11, p0[r1 + xc1], acc0);
                acc1 = fmaf(w00, p1[r0 + xc0], acc1);
                acc1 = fmaf(w01, p1[r0 + xc1], acc1);
                acc1 = fmaf(w10, p1[r1 + xc0], acc1);
                acc1 = fmaf(w11, p1[r1 + xc1], acc1);
            }
        }
    }

    int o = v * DETS + j;
    out[o] = acc0 * dl;
    out[VIEWS * DETS + o] = acc1 * dl;
}

extern "C" void kernel_launch(void* const* d_in, const int* in_sizes, int n_in,
                              void* d_out, int out_size, void* d_ws, size_t ws_size,
                              hipStream_t stream) {
    const float* img = (const float*)d_in[0];
    const float* opt = (const float*)d_in[1];
    float* out = (float*)d_out;

    bool use_il = (ws_size >= sizeof(float2) * HH * WW);
    int nthreads = VIEWS * DETS;
    int nblocks = nthreads / 256;

    if (use_il) {
        float2* img2 = (float2*)d_ws;
        interleave_kernel<<<(HH * WW + 255) / 256, 256, 0, stream>>>(img, img2);
        project_kernel<true><<<nblocks, 256, 0, stream>>>(img, img2, opt, out);
    } else {
        project_kernel<false><<<nblocks, 256, 0, stream>>>(img, nullptr, opt, out);
    }
}

// Round 2
// 131.849 us; speedup vs baseline: 1.3855x; 1.3855x over previous
//
#include <hip/hip_runtime.h>

#define VIEWS 512
#define DETS  512
#define HH    256
#define WW    256
#define NS    384
#define PW    (WW + 2)
#define PH    (HH + 2)

// 16B vector type that only promises 8B alignment; backend emits dwordx4 if
// unaligned VMEM is supported (gfx950), else splits into two dwordx2 — both correct.
typedef float4 float4_a8 __attribute__((aligned(8)));

__global__ void build_padded(const float* __restrict__ img, float2* __restrict__ dst) {
    int i = blockIdx.x * blockDim.x + threadIdx.x;
    if (i >= PW * PH) return;
    int r = i / PW, c = i - r * PW;
    float2 v = make_float2(0.0f, 0.0f);
    if (r >= 1 && r <= HH && c >= 1 && c <= WW) {
        int k = (r - 1) * WW + (c - 1);
        v = make_float2(img[k], img[HH * WW + k]);
    }
    dst[i] = v;
}

__global__ __launch_bounds__(256) void project_padded(
    const float2* __restrict__ img2,  // (PH, PW) zero-bordered, interleaved channels
    const float* __restrict__ opt,
    float* __restrict__ out)
{
    int idx = blockIdx.x * blockDim.x + threadIdx.x;
    int v = idx >> 9;          // view
    int j = idx & (DETS - 1);  // detector
    int seg = blockIdx.y;      // sample segment (0/1)

    float dImg = opt[4], dDet = opt[5], ang0 = opt[6], dAng = opt[7];
    float s2r = opt[8], d2r = opt[9], binshift = opt[10];

    float beta = ang0 + dAng * (float)v;
    float cb = cosf(beta), sb = sinf(beta);
    float u = ((float)j - (DETS - 1) * 0.5f) * dDet + binshift;

    float srcx = s2r * cb, srcy = s2r * sb;
    float dx = -d2r * cb - u * sb - srcx;
    float dy = -d2r * sb + u * cb - srcy;
    float inv = rsqrtf(dx * dx + dy * dy);
    dx *= inv; dy *= inv;

    float R  = 0.5f * sqrtf((float)(HH * HH + WW * WW)) * dImg;
    float dl = 2.0f * R / (float)NS;
    float t0 = s2r - R + 0.5f * dl;
    float invD = 1.0f / dImg;

    float px0 = (srcx + dx * t0) * invD + (WW - 1) * 0.5f;
    float py0 = (srcy + dy * t0) * invD + (HH - 1) * 0.5f;
    float sx = dx * dl * invD;
    float sy = dy * dl * invD;

    int s_begin = seg * (NS / 2);
    int s_end   = s_begin + (NS / 2);

    float acc0 = 0.0f, acc1 = 0.0f;

    for (int s = s_begin; s < s_end; ++s) {
        float px = fmaf((float)s, sx, px0);
        float py = fmaf((float)s, sy, py0);
        // nonzero contribution requires px in (-1, W) and py in (-1, H)
        if (px > -1.0f && px < (float)WW && py > -1.0f && py < (float)HH) {
            float xf = floorf(px), yf = floorf(py);
            float wx = px - xf, wy = py - yf;
            // shift into padded coords: x0p in [0, W], y0p in [0, H]
            int x0p = (int)xf + 1;
            int y0p = (int)yf + 1;

            const float2* r0 = img2 + (y0p * PW + x0p);
            float4 q0 = *(const float4_a8*)r0;        // (v00.c0, v00.c1, v01.c0, v01.c1)
            float4 q1 = *(const float4_a8*)(r0 + PW); // (v10.c0, v10.c1, v11.c0, v11.c1)

            float ax = 1.0f - wx, ay = 1.0f - wy;
            float w00 = ax * ay, w01 = wx * ay;
            float w10 = ax * wy, w11 = wx * wy;

            acc0 = fmaf(w00, q0.x, acc0);
            acc1 = fmaf(w00, q0.y, acc1);
            acc0 = fmaf(w01, q0.z, acc0);
            acc1 = fmaf(w01, q0.w, acc1);
            acc0 = fmaf(w10, q1.x, acc0);
            acc1 = fmaf(w10, q1.y, acc1);
            acc0 = fmaf(w11, q1.z, acc0);
            acc1 = fmaf(w11, q1.w, acc1);
        }
    }

    int o = v * DETS + j;
    atomicAdd(&out[o], acc0 * dl);
    atomicAdd(&out[VIEWS * DETS + o], acc1 * dl);
}

// Fallback if ws is too small: one thread per ray, planar loads, direct store.
__global__ __launch_bounds__(256) void project_fallback(
    const float* __restrict__ img,
    const float* __restrict__ opt,
    float* __restrict__ out)
{
    int idx = blockIdx.x * blockDim.x + threadIdx.x;
    int v = idx >> 9;
    int j = idx & (DETS - 1);

    float dImg = opt[4], dDet = opt[5], ang0 = opt[6], dAng = opt[7];
    float s2r = opt[8], d2r = opt[9], binshift = opt[10];

    float beta = ang0 + dAng * (float)v;
    float cb = cosf(beta), sb = sinf(beta);
    float u = ((float)j - (DETS - 1) * 0.5f) * dDet + binshift;

    float srcx = s2r * cb, srcy = s2r * sb;
    float dx = -d2r * cb - u * sb - srcx;
    float dy = -d2r * sb + u * cb - srcy;
    float inv = rsqrtf(dx * dx + dy * dy);
    dx *= inv; dy *= inv;

    float R  = 0.5f * sqrtf((float)(HH * HH + WW * WW)) * dImg;
    float dl = 2.0f * R / (float)NS;
    float t0 = s2r - R + 0.5f * dl;
    float invD = 1.0f / dImg;

    float px0 = (srcx + dx * t0) * invD + (WW - 1) * 0.5f;
    float py0 = (srcy + dy * t0) * invD + (HH - 1) * 0.5f;
    float sx = dx * dl * invD;
    float sy = dy * dl * invD;

    float acc0 = 0.0f, acc1 = 0.0f;
    for (int s = 0; s < NS; ++s) {
        float px = fmaf((float)s, sx, px0);
        float py = fmaf((float)s, sy, py0);
        if (px > -1.0f && px < (float)WW && py > -1.0f && py < (float)HH) {
            float x0 = floorf(px), y0 = floorf(py);
            float wx = px - x0, wy = py - y0;
            int x0i = (int)x0, y0i = (int)y0;
            int x1i = x0i + 1, y1i = y0i + 1;
            bool bx0 = (x0i >= 0), bx1 = (x1i <= WW - 1);
            bool by0 = (y0i >= 0), by1 = (y1i <= HH - 1);
            int xc0 = bx0 ? x0i : 0, xc1 = bx1 ? x1i : (WW - 1);
            int yc0 = by0 ? y0i : 0, yc1 = by1 ? y1i : (HH - 1);
            float w00 = (1.0f - wx) * (1.0f - wy);
            float w01 = wx * (1.0f - wy);
            float w10 = (1.0f - wx) * wy;
            float w11 = wx * wy;
            w00 = (bx0 & by0) ? w00 : 0.0f;
            w01 = (bx1 & by0) ? w01 : 0.0f;
            w10 = (bx0 & by1) ? w10 : 0.0f;
            w11 = (bx1 & by1) ? w11 : 0.0f;
            int r0 = yc0 * WW, r1 = yc1 * WW;
            const float* p0 = img;
            const float* p1 = img + HH * WW;
            acc0 = fmaf(w00, p0[r0 + xc0], acc0);
            acc0 = fmaf(w01, p0[r0 + xc1], acc0);
            acc0 = fmaf(w10, p0[r1 + xc0], acc0);
            acc0 = fmaf(w11, p0[r1 + xc1], acc0);
            acc1 = fmaf(w00, p1[r0 + xc0], acc1);
            acc1 = fmaf(w01, p1[r0 + xc1], acc1);
            acc1 = fmaf(w10, p1[r1 + xc0], acc1);
            acc1 = fmaf(w11, p1[r1 + xc1], acc1);
        }
    }
    int o = v * DETS + j;
    out[o] = acc0 * dl;
    out[VIEWS * DETS + o] = acc1 * dl;
}

extern "C" void kernel_launch(void* const* d_in, const int* in_sizes, int n_in,
                              void* d_out, int out_size, void* d_ws, size_t ws_size,
                              hipStream_t stream) {
    const float* img = (const float*)d_in[0];
    const float* opt = (const float*)d_in[1];
    float* out = (float*)d_out;

    size_t need = sizeof(float2) * PW * PH;
    if (ws_size >= need) {
        float2* img2 = (float2*)d_ws;
        build_padded<<<(PW * PH + 255) / 256, 256, 0, stream>>>(img, img2);
        hipMemsetAsync(out, 0, (size_t)out_size * sizeof(float), stream);
        dim3 grid(VIEWS * DETS / 256, 2);
        project_padded<<<grid, 256, 0, stream>>>(img2, opt, out);
    } else {
        project_fallback<<<VIEWS * DETS / 256, 256, 0, stream>>>(img, opt, out);
    }
}

// Round 3
// 118.556 us; speedup vs baseline: 1.5408x; 1.1121x over previous
//
#include <hip/hip_runtime.h>

#define VIEWS 512
#define DETS  512
#define HH    256
#define WW    256
#define NS    384
#define P     264   // 2-ring zero pad (+ slack): valid pixel (y,x) at [y+2][x+2]

typedef float4 float4_a8 __attribute__((aligned(8)));

// Build normal + transposed padded interleaved images in one pass.
__global__ void build_dual(const float* __restrict__ img,
                           float2* __restrict__ L0, float2* __restrict__ L1) {
    int i = blockIdx.x * blockDim.x + threadIdx.x;
    if (i >= P * P) return;
    int r = i / P, c = i - r * P;
    int y = r - 2, x = c - 2;
    float2 val = make_float2(0.0f, 0.0f);
    if (x >= 0 && x < WW && y >= 0 && y < HH) {
        int k = y * WW + x;
        val = make_float2(img[k], img[HH * WW + k]);
    }
    L0[r * P + c] = val;       // L0[y][x]
    L1[c * P + r] = val;       // L1[x][y] (transposed)
}

__global__ __launch_bounds__(256) void project_dual(
    const float2* __restrict__ imgN,
    const float2* __restrict__ imgT,
    const float* __restrict__ opt,
    float* __restrict__ out)
{
    int idx = blockIdx.x * blockDim.x + threadIdx.x;
    int v = idx >> 9;          // view (uniform per block: 256 thr = half view)
    int j = idx & (DETS - 1);  // detector
    int seg = blockIdx.y;      // sample parity

    float dImg = opt[4], dDet = opt[5], ang0 = opt[6], dAng = opt[7];
    float s2r = opt[8], d2r = opt[9], binshift = opt[10];

    float beta = ang0 + dAng * (float)v;
    float cb = cosf(beta), sb = sinf(beta);
    float u = ((float)j - (DETS - 1) * 0.5f) * dDet + binshift;

    float srcx = s2r * cb, srcy = s2r * sb;
    float dx = -d2r * cb - u * sb - srcx;
    float dy = -d2r * sb + u * cb - srcy;
    float inv = rsqrtf(dx * dx + dy * dy);
    dx *= inv; dy *= inv;

    float R  = 0.5f * sqrtf((float)(HH * HH + WW * WW)) * dImg;
    float dl = 2.0f * R / (float)NS;
    float t0 = s2r - R + 0.5f * dl;
    float invD = 1.0f / dImg;

    float px0 = (srcx + dx * t0) * invD + (WW - 1) * 0.5f;
    float py0 = (srcy + dy * t0) * invD + (HH - 1) * 0.5f;
    float sx = dx * dl * invD;
    float sy = dy * dl * invD;

    // Lanes (consecutive dets) spread along (-sb, cb). Pick the layout where
    // the spread is row-aligned: transposed when |cb| > |sb|.
    bool trans = fabsf(cb) > fabsf(sb);
    const float2* img2 = trans ? imgT : imgN;
    if (trans) { float t = px0; px0 = py0; py0 = t; t = sx; sx = sy; sy = t; }

    // Analytic sample range: reference contributes iff px in (-1,W) AND py in (-1,H).
    // Conservative by <=1 sample each side; slack samples read only the zero pad.
    float lo = 0.0f, hi = (float)(NS - 1);
    if (fabsf(sx) > 1e-7f) {
        float a = (-1.0f - px0) / sx, b = ((float)WW - px0) / sx;
        lo = fmaxf(lo, fminf(a, b)); hi = fminf(hi, fmaxf(a, b));
    } else if (!(px0 > -1.0f && px0 < (float)WW)) { lo = 1.0f; hi = 0.0f; }
    if (fabsf(sy) > 1e-7f) {
        float a = (-1.0f - py0) / sy, b = ((float)HH - py0) / sy;
        lo = fmaxf(lo, fminf(a, b)); hi = fminf(hi, fmaxf(a, b));
    } else if (!(py0 > -1.0f && py0 < (float)HH)) { lo = 1.0f; hi = 0.0f; }
    lo = fminf(fmaxf(lo, 0.0f), (float)NS);
    hi = fminf(fmaxf(hi, 0.0f), (float)NS);

    int s_begin = max((int)floorf(lo), 0);
    int s_end   = min((int)ceilf(hi) + 1, NS);

    float acc0 = 0.0f, acc1 = 0.0f;

    #pragma unroll 2
    for (int s = s_begin + seg; s < s_end; s += 2) {
        float px = fmaf((float)s, sx, px0);
        float py = fmaf((float)s, sy, py0);
        float xf = floorf(px), yf = floorf(py);
        float wx = px - xf, wy = py - yf;
        int x0p = (int)xf + 2;
        int y0p = (int)yf + 2;

        const float2* r0 = img2 + (y0p * P + x0p);
        float4 q0 = *(const float4_a8*)r0;        // (v00.c0 v00.c1 v01.c0 v01.c1)
        float4 q1 = *(const float4_a8*)(r0 + P);  // (v10.c0 v10.c1 v11.c0 v11.c1)

        float ax = 1.0f - wx, ay = 1.0f - wy;
        float w00 = ax * ay, w01 = wx * ay;
        float w10 = ax * wy, w11 = wx * wy;

        acc0 = fmaf(w00, q0.x, acc0);
        acc1 = fmaf(w00, q0.y, acc1);
        acc0 = fmaf(w01, q0.z, acc0);
        acc1 = fmaf(w01, q0.w, acc1);
        acc0 = fmaf(w10, q1.x, acc0);
        acc1 = fmaf(w10, q1.y, acc1);
        acc0 = fmaf(w11, q1.z, acc0);
        acc1 = fmaf(w11, q1.w, acc1);
    }

    int o = v * DETS + j;
    atomicAdd(&out[o], acc0 * dl);
    atomicAdd(&out[VIEWS * DETS + o], acc1 * dl);
}

// Fallback (ws too small): one thread per ray, planar loads, direct store.
__global__ __launch_bounds__(256) void project_fallback(
    const float* __restrict__ img,
    const float* __restrict__ opt,
    float* __restrict__ out)
{
    int idx = blockIdx.x * blockDim.x + threadIdx.x;
    int v = idx >> 9;
    int j = idx & (DETS - 1);

    float dImg = opt[4], dDet = opt[5], ang0 = opt[6], dAng = opt[7];
    float s2r = opt[8], d2r = opt[9], binshift = opt[10];

    float beta = ang0 + dAng * (float)v;
    float cb = cosf(beta), sb = sinf(beta);
    float u = ((float)j - (DETS - 1) * 0.5f) * dDet + binshift;

    float srcx = s2r * cb, srcy = s2r * sb;
    float dx = -d2r * cb - u * sb - srcx;
    float dy = -d2r * sb + u * cb - srcy;
    float inv = rsqrtf(dx * dx + dy * dy);
    dx *= inv; dy *= inv;

    float R  = 0.5f * sqrtf((float)(HH * HH + WW * WW)) * dImg;
    float dl = 2.0f * R / (float)NS;
    float t0 = s2r - R + 0.5f * dl;
    float invD = 1.0f / dImg;

    float px0 = (srcx + dx * t0) * invD + (WW - 1) * 0.5f;
    float py0 = (srcy + dy * t0) * invD + (HH - 1) * 0.5f;
    float sx = dx * dl * invD;
    float sy = dy * dl * invD;

    float acc0 = 0.0f, acc1 = 0.0f;
    for (int s = 0; s < NS; ++s) {
        float px = fmaf((float)s, sx, px0);
        float py = fmaf((float)s, sy, py0);
        if (px > -1.0f && px < (float)WW && py > -1.0f && py < (float)HH) {
            float x0 = floorf(px), y0 = floorf(py);
            float wx = px - x0, wy = py - y0;
            int x0i = (int)x0, y0i = (int)y0;
            int x1i = x0i + 1, y1i = y0i + 1;
            bool bx0 = (x0i >= 0), bx1 = (x1i <= WW - 1);
            bool by0 = (y0i >= 0), by1 = (y1i <= HH - 1);
            int xc0 = bx0 ? x0i : 0, xc1 = bx1 ? x1i : (WW - 1);
            int yc0 = by0 ? y0i : 0, yc1 = by1 ? y1i : (HH - 1);
            float w00 = (1.0f - wx) * (1.0f - wy);
            float w01 = wx * (1.0f - wy);
            float w10 = (1.0f - wx) * wy;
            float w11 = wx * wy;
            w00 = (bx0 & by0) ? w00 : 0.0f;
            w01 = (bx1 & by0) ? w01 : 0.0f;
            w10 = (bx0 & by1) ? w10 : 0.0f;
            w11 = (bx1 & by1) ? w11 : 0.0f;
            int r0 = yc0 * WW, r1 = yc1 * WW;
            const float* p0 = img;
            const float* p1 = img + HH * WW;
            acc0 = fmaf(w00, p0[r0 + xc0], acc0);
            acc0 = fmaf(w01, p0[r0 + xc1], acc0);
            acc0 = fmaf(w10, p0[r1 + xc0], acc0);
            acc0 = fmaf(w11, p0[r1 + xc1], acc0);
            acc1 = fmaf(w00, p1[r0 + xc0], acc1);
            acc1 = fmaf(w01, p1[r0 + xc1], acc1);
            acc1 = fmaf(w10, p1[r1 + xc0], acc1);
            acc1 = fmaf(w11, p1[r1 + xc1], acc1);
        }
    }
    int o = v * DETS + j;
    out[o] = acc0 * dl;
    out[VIEWS * DETS + o] = acc1 * dl;
}

extern "C" void kernel_launch(void* const* d_in, const int* in_sizes, int n_in,
                              void* d_out, int out_size, void* d_ws, size_t ws_size,
                              hipStream_t stream) {
    const float* img = (const float*)d_in[0];
    const float* opt = (const float*)d_in[1];
    float* out = (float*)d_out;

    size_t need = 2 * sizeof(float2) * P * P;
    if (ws_size >= need) {
        float2* L0 = (float2*)d_ws;
        float2* L1 = L0 + P * P;
        build_dual<<<(P * P + 255) / 256, 256, 0, stream>>>(img, L0, L1);
        hipMemsetAsync(out, 0, (size_t)out_size * sizeof(float), stream);
        dim3 grid(VIEWS * DETS / 256, 2);
        project_dual<<<grid, 256, 0, stream>>>(L0, L1, opt, out);
    } else {
        project_fallback<<<VIEWS * DETS / 256, 256, 0, stream>>>(img, opt, out);
    }
}